// Round 7
// baseline (203.108 us; speedup 1.0000x reference)
//
#include <hip/hip_runtime.h>
#include <stdint.h>

#define B_SZ   2048
#define IN_SZ  1024
#define OUT_SZ 1024
#define Q_SZ   16
#define NZB    4                              // i-windows of 256

typedef __attribute__((ext_vector_type(8))) short short8;   // 8 bf16 (4 VGPRs)
typedef __attribute__((ext_vector_type(4))) float floatx4;  // MFMA accumulator
typedef __attribute__((ext_vector_type(2))) unsigned short u16x2;
typedef __attribute__((ext_vector_type(2))) short s16x2;

__device__ __forceinline__ unsigned short f32_to_bf16_rne(float f) {
    union { float f; uint32_t u; } v; v.f = f;
    uint32_t u = v.u;
    return (unsigned short)((u + 0x7FFFu + ((u >> 16) & 1u)) >> 16);
}

// packed 2x16-bit: out = (onehot has bit q) ? xv16 : 0, in 3 VALU ops.
__device__ __forceinline__ uint32_t mask3(uint32_t xv, uint32_t ohv, unsigned short sh) {
    union { uint32_t u; u16x2 v; s16x2 s; } t;
    t.u = ohv;
    u16x2 shv; shv.x = sh; shv.y = sh;
    t.v = t.v << shv;
    s16x2 f15; f15.x = 15; f15.y = 15;
    t.s = t.s >> f15;
    return xv & t.u;
}

// async global->LDS, 16B per lane, linear (wave-uniform base + lane*16)
__device__ __forceinline__ void gload_lds16(const void* g, void* l) {
    __builtin_amdgcn_global_load_lds(
        (const __attribute__((address_space(1))) unsigned int*)g,
        (__attribute__((address_space(3))) unsigned int*)l, 16, 0, 0);
}

// ---------------- prep: fragment-linear Wf (LDS-transpose, coalesced) -------
// Slab S = (zb*8+xb)*64 + ih*16 + q; chunk c = (h*8+nt)*64 + L; element j:
//   o = xb*128 + nt*16 + (L&15),  i = zb*256 + ih*64 + h*32 + (L>>4)*8 + j
__global__ void k_build_wf(const float* __restrict__ W, unsigned short* __restrict__ Wf) {
    const int S = blockIdx.x;
    const int q = S & 15, ih = (S >> 4) & 3, xb = (S >> 6) & 7, zb = S >> 9;
    const int t = threadIdx.x;
    const int i0 = zb * 256 + ih * 64;
    const int o0 = xb * 128;
    __shared__ unsigned short lds[64][130];    // pad 130: both phases ~2-way banks

#pragma unroll
    for (int it = 0; it < 8; ++it) {
        int r  = it * 8 + (t >> 5);
        int c4 = (t & 31) * 4;
        float4 v = *(const float4*)(W + ((size_t)(q * 1024 + i0 + r)) * 1024 + o0 + c4);
        unsigned short h0 = f32_to_bf16_rne(v.x), h1 = f32_to_bf16_rne(v.y);
        unsigned short h2 = f32_to_bf16_rne(v.z), h3 = f32_to_bf16_rne(v.w);
        *(uint32_t*)&lds[r][c4]     = (uint32_t)h0 | ((uint32_t)h1 << 16);
        *(uint32_t*)&lds[r][c4 + 2] = (uint32_t)h2 | ((uint32_t)h3 << 16);
    }
    __syncthreads();

    unsigned short* dst = Wf + (size_t)S * 8192;
#pragma unroll
    for (int it = 0; it < 4; ++it) {
        int c = it * 256 + t;
        int L = c & 63;
        int hnt = c >> 6;
        int h = hnt >> 3, nt = hnt & 7;
        int ol = nt * 16 + (L & 15);
        int il = h * 32 + (L >> 4) * 8;
        unsigned short v[8];
#pragma unroll
        for (int j = 0; j < 8; ++j) v[j] = lds[il + j][ol];
        *(uint4*)(dst + (size_t)c * 8) = *(uint4*)v;
    }
}

// ---------------- fused GEMM: fat waves (64b x 128o), LDS reads halved -------
// Block: 128b x 128o, TWO waves of 64b x 128o each (mt=4, nt=8). R6 was at
// the measured ds_read ceiling (128 KB/slab-step/CU = 88 B/cy ~ m134's 85):
// B-read volume per wave is o_width*K*2 regardless of b-rows, so halving the
// wave count at constant output halves LDS reads (64 KB -> 753cy) while MFMA
// (1242cy) and total mask-VALU (scales with b-rows*K, conserved) stay fixed.
// MFMA is now the binding pipe. ~290 VGPR -> 1 wave/SIMD; 2 blocks/CU give
// 4 waves on 4 SIMDs. R6's 4-ring + cross-slab pipelined ds_reads kept.
__global__ __launch_bounds__(128, 1) void k_gemm(const unsigned short* __restrict__ Wf,
                                                 const float* __restrict__ x,
                                                 const int* __restrict__ idx,
                                                 float* __restrict__ P) {
    const int tid  = threadIdx.x;
    const int wave = tid >> 6, lane = tid & 63;

    // id = zb + 4*xb + 32*yb -> XCD (id%8) = zb+4*(xb&1), constant per window.
    const int id = blockIdx.x;
    const int zb = id & 3;
    const int xb = (id >> 2) & 7;
    const int yb = id >> 5;
    const int o0 = xb * 128, b0 = yb * 128, ibase = zb * 256;

    const char* wbase = (const char*)Wf + (size_t)(zb * 8 + xb) * 64 * 16384;
    const int   lofs  = lane * 16;

    __shared__ unsigned char sm[4][16384];     // 4-deep slab ring (64 KB)

    const int arow = b0 + wave * 64 + (lane & 15);
    const float* xg = x + (size_t)arow * IN_SZ + ibase + (lane >> 4) * 8;
    const int*   ig = idx + (size_t)arow * IN_SZ + ibase + (lane >> 4) * 8;

    floatx4 acc[32];
#pragma unroll
    for (int i = 0; i < 32; ++i) acc[i] = (floatx4){0.f, 0.f, 0.f, 0.f};

    uint4 xr[4][2], oh[4][2];                  // 64 rows x 64 i packed A state
    short8 fc[8], fn[8];                       // pipelined B fragments

#define RELOADA(ih)                                                           \
    {   int io_ = (ih) * 64;                                                  \
        _Pragma("unroll")                                                     \
        for (int mt_ = 0; mt_ < 4; ++mt_)                                     \
            _Pragma("unroll")                                                 \
            for (int hh_ = 0; hh_ < 2; ++hh_) {                               \
                const float* xp_ = xg + mt_ * 16 * IN_SZ + io_ + hh_ * 32;    \
                const int*   ip_ = ig + mt_ * 16 * IN_SZ + io_ + hh_ * 32;    \
                float a_[8]; int b_[8];                                       \
                *(float4*)(a_)     = *(const float4*)xp_;                     \
                *(float4*)(a_ + 4) = *((const float4*)xp_ + 1);               \
                *(int4*)(b_)       = *(const int4*)ip_;                       \
                *(int4*)(b_ + 4)   = *((const int4*)ip_ + 1);                 \
                unsigned short xv_[8];                                        \
                _Pragma("unroll")                                             \
                for (int j_ = 0; j_ < 8; ++j_) xv_[j_] = f32_to_bf16_rne(a_[j_]); \
                xr[mt_][hh_] = *(uint4*)xv_;                                  \
                uint32_t iw_[4];                                              \
                _Pragma("unroll")                                             \
                for (int w_ = 0; w_ < 4; ++w_)                                \
                    iw_[w_] = (1u << b_[2 * w_]) | ((1u << b_[2 * w_ + 1]) << 16); \
                oh[mt_][hh_] = *(uint4*)iw_;                                  \
            }                                                                 \
    }

#define MASKS(hh)                                                             \
        _Pragma("unroll")                                                     \
        for (int mt_ = 0; mt_ < 4; ++mt_) {                                   \
            aF[mt_].u.x = mask3(xr[mt_][hh].x, oh[mt_][hh].x, sh_);           \
            aF[mt_].u.y = mask3(xr[mt_][hh].y, oh[mt_][hh].y, sh_);           \
            aF[mt_].u.z = mask3(xr[mt_][hh].z, oh[mt_][hh].z, sh_);           \
            aF[mt_].u.w = mask3(xr[mt_][hh].w, oh[mt_][hh].w, sh_);           \
        }

    // each wave stages 8KB of the 16KB slab: 8 x global_load_lds(16B)
    const int soff = wave * 8192 + lofs;
#define STAGE(s_, r_)                                                         \
    {   const char* gp_ = wbase + (size_t)(s_) * 16384 + soff;                \
        unsigned char* lp_ = (unsigned char*)sm + (r_) * 16384 + soff;        \
        _Pragma("unroll")                                                     \
        for (int u_ = 0; u_ < 8; ++u_)                                        \
            gload_lds16(gp_ + u_ * 1024, lp_ + u_ * 1024);                    \
    }

#define DSREAD(dst, rr, hofs)                                                 \
    {   const unsigned char* bp_ = (const unsigned char*)sm + (rr) * 16384 +  \
                                   (hofs) + lofs;                             \
        _Pragma("unroll")                                                     \
        for (int nt_ = 0; nt_ < 8; ++nt_)                                     \
            (dst)[nt_] = *(const short8*)(bp_ + nt_ * 1024);                  \
    }

#define MFMA32(fa)                                                            \
        _Pragma("unroll")                                                     \
        for (int mt_ = 0; mt_ < 4; ++mt_)                                     \
            _Pragma("unroll")                                                 \
            for (int nt_ = 0; nt_ < 8; ++nt_)                                 \
                acc[mt_ * 8 + nt_] = __builtin_amdgcn_mfma_f32_16x16x32_bf16( \
                    aF[mt_].s8, (fa)[nt_], acc[mt_ * 8 + nt_], 0, 0, 0);

// slab s: fn <- (s,h1) issued first; h0 MFMAs consume fc (read last slab);
// fc <- (s+1,h0) issued before h1 MFMAs; h1 MFMAs consume fn. Stage s+2.
#define SLAB(s_, rc_, rn_, rs_)                                               \
    {   if ((s_) < 62) STAGE((s_) + 2, rs_);                                  \
        DSREAD(fn, rc_, 8192);                                                \
        const unsigned short sh_ = (unsigned short)(15 - ((s_) & 15));        \
        union { uint4 u; short8 s8; } aF[4];                                  \
        MASKS(0);                                                             \
        MFMA32(fc);                                                           \
        if ((s_) < 63) DSREAD(fc, rn_, 0);                                    \
        MASKS(1);                                                             \
        MFMA32(fn);                                                           \
        __syncthreads();                                                      \
    }

    RELOADA(0);
    STAGE(0, 0);
    STAGE(1, 1);
    __syncthreads();                           // slabs 0,1 resident
    DSREAD(fc, 0, 0);                          // (0,h0)

#pragma unroll 1
    for (int gg = 0; gg < 16; ++gg) {
        if (gg && (gg & 3) == 0) RELOADA(gg >> 2);   // s = 16,32,48
        const int s0 = gg * 4;
        SLAB(s0 + 0, 0, 1, 2);
        SLAB(s0 + 1, 1, 2, 3);
        SLAB(s0 + 2, 2, 3, 0);
        SLAB(s0 + 3, 3, 0, 1);
    }

    // epilogue: plain stores to private partial buffer (C/D: col=lane&15 -> o,
    // row=(lane>>4)*4+e -> b). No atomics anywhere.
    float* Pz = P + (size_t)zb * (B_SZ * OUT_SZ);
    int cn = lane & 15, rq = lane >> 4;
#pragma unroll
    for (int mt = 0; mt < 4; ++mt)
#pragma unroll
        for (int nt = 0; nt < 8; ++nt) {
            int bb = b0 + wave * 64 + mt * 16 + rq * 4;
            int oo = o0 + nt * 16 + cn;
#pragma unroll
            for (int e = 0; e < 4; ++e)
                Pz[(size_t)(bb + e) * OUT_SZ + oo] = acc[mt * 8 + nt][e];
        }
#undef RELOADA
#undef MASKS
#undef STAGE
#undef DSREAD
#undef MFMA32
#undef SLAB
}

// ---------------- reduce: out = bias + sum_z P[z] ----------------
__global__ void k_reduce(const float* __restrict__ P, const float* __restrict__ bias,
                         float* __restrict__ out) {
    int t = blockIdx.x * 256 + threadIdx.x;    // float4 index, 524288 total
    const float4* b4 = (const float4*)bias;
    float4 a = b4[t & 255];
#pragma unroll
    for (int z = 0; z < NZB; ++z) {
        float4 v = ((const float4*)P)[(size_t)z * (B_SZ * OUT_SZ / 4) + t];
        a.x += v.x; a.y += v.y; a.z += v.z; a.w += v.w;
    }
    ((float4*)out)[t] = a;
}

// ---------------- fallback (ws too small): exact fp32 gather ----------------
__global__ void k_naive(const float* __restrict__ x, const int* __restrict__ idx,
                        const float* __restrict__ W, const float* __restrict__ bias,
                        float* __restrict__ out) {
    int b = blockIdx.x;
    int o = threadIdx.x * 4;
    float4 acc = *(const float4*)(bias + o);
    const float* xr = x + (size_t)b * IN_SZ;
    const int*   ir = idx + (size_t)b * IN_SZ;
    for (int i = 0; i < IN_SZ; ++i) {
        float xv = xr[i];
        int q = ir[i];
        float4 w4 = *(const float4*)(W + ((size_t)q * IN_SZ + i) * OUT_SZ + o);
        acc.x += xv * w4.x; acc.y += xv * w4.y;
        acc.z += xv * w4.z; acc.w += xv * w4.w;
    }
    *(float4*)(out + (size_t)b * OUT_SZ + o) = acc;
}

extern "C" void kernel_launch(void* const* d_in, const int* in_sizes, int n_in,
                              void* d_out, int out_size, void* d_ws, size_t ws_size,
                              hipStream_t stream) {
    const float* x    = (const float*)d_in[0];
    const int*   idx  = (const int*)d_in[1];
    const float* W    = (const float*)d_in[2];
    const float* bias = (const float*)d_in[3];
    float* out = (float*)d_out;

    const size_t wf_bytes = (size_t)2048 * 16384;                 // 32 MB frag-linear W
    const size_t p_bytes  = (size_t)NZB * B_SZ * OUT_SZ * 4;      // 32 MB partials
    if (ws_size < wf_bytes + p_bytes) {
        k_naive<<<dim3(B_SZ), dim3(256), 0, stream>>>(x, idx, W, bias, out);
        return;
    }
    unsigned short* Wf = (unsigned short*)d_ws;
    float* P = (float*)((char*)d_ws + wf_bytes);

    k_build_wf<<<dim3(2048), dim3(256), 0, stream>>>(W, Wf);
    k_gemm<<<dim3(NZB * 8 * (B_SZ / 128)), dim3(128), 0, stream>>>(Wf, x, idx, P);
    k_reduce<<<dim3(2048), dim3(256), 0, stream>>>(P, bias, out);
}

// Round 8
// 203.078 us; speedup vs baseline: 1.0001x; 1.0001x over previous
//
#include <hip/hip_runtime.h>
#include <stdint.h>

#define B_SZ   2048
#define IN_SZ  1024
#define OUT_SZ 1024
#define Q_SZ   16
#define NZB    4                              // i-windows of 256

typedef __attribute__((ext_vector_type(8))) short short8;   // 8 bf16 (4 VGPRs)
typedef __attribute__((ext_vector_type(4))) float floatx4;  // MFMA accumulator
typedef __attribute__((ext_vector_type(2))) unsigned short u16x2;
typedef __attribute__((ext_vector_type(2))) short s16x2;

__device__ __forceinline__ unsigned short f32_to_bf16_rne(float f) {
    union { float f; uint32_t u; } v; v.f = f;
    uint32_t u = v.u;
    return (unsigned short)((u + 0x7FFFu + ((u >> 16) & 1u)) >> 16);
}

// packed 2x16-bit: out = (onehot has bit q) ? xv16 : 0, in 3 VALU ops.
__device__ __forceinline__ uint32_t mask3(uint32_t xv, uint32_t ohv, unsigned short sh) {
    union { uint32_t u; u16x2 v; s16x2 s; } t;
    t.u = ohv;
    u16x2 shv; shv.x = sh; shv.y = sh;
    t.v = t.v << shv;
    s16x2 f15; f15.x = 15; f15.y = 15;
    t.s = t.s >> f15;
    return xv & t.u;
}

// async global->LDS, 16B per lane, linear (wave-uniform base + lane*16)
__device__ __forceinline__ void gload_lds16(const void* g, void* l) {
    __builtin_amdgcn_global_load_lds(
        (const __attribute__((address_space(1))) unsigned int*)g,
        (__attribute__((address_space(3))) unsigned int*)l, 16, 0, 0);
}

// ---------------- prep: fragment-linear Wf (LDS-transpose, coalesced) -------
// Slab S = (zb*8+xbW)*64 + ih*16 + q; chunk c = (h*8+nt)*64 + L; element j:
//   o = xbW*128 + nt*16 + (L&15),  i = zb*256 + ih*64 + h*32 + (L>>4)*8 + j
__global__ void k_build_wf(const float* __restrict__ W, unsigned short* __restrict__ Wf) {
    const int S = blockIdx.x;
    const int q = S & 15, ih = (S >> 4) & 3, xb = (S >> 6) & 7, zb = S >> 9;
    const int t = threadIdx.x;
    const int i0 = zb * 256 + ih * 64;
    const int o0 = xb * 128;
    __shared__ unsigned short lds[64][130];    // pad 130: both phases ~2-way banks

#pragma unroll
    for (int it = 0; it < 8; ++it) {
        int r  = it * 8 + (t >> 5);
        int c4 = (t & 31) * 4;
        float4 v = *(const float4*)(W + ((size_t)(q * 1024 + i0 + r)) * 1024 + o0 + c4);
        unsigned short h0 = f32_to_bf16_rne(v.x), h1 = f32_to_bf16_rne(v.y);
        unsigned short h2 = f32_to_bf16_rne(v.z), h3 = f32_to_bf16_rne(v.w);
        *(uint32_t*)&lds[r][c4]     = (uint32_t)h0 | ((uint32_t)h1 << 16);
        *(uint32_t*)&lds[r][c4 + 2] = (uint32_t)h2 | ((uint32_t)h3 << 16);
    }
    __syncthreads();

    unsigned short* dst = Wf + (size_t)S * 8192;
#pragma unroll
    for (int it = 0; it < 4; ++it) {
        int c = it * 256 + t;
        int L = c & 63;
        int hnt = c >> 6;
        int h = hnt >> 3, nt = hnt & 7;
        int ol = nt * 16 + (L & 15);
        int il = h * 32 + (L >> 4) * 8;
        unsigned short v[8];
#pragma unroll
        for (int j = 0; j < 8; ++j) v[j] = lds[il + j][ol];
        *(uint4*)(dst + (size_t)c * 8) = *(uint4*)v;
    }
}

// ---------------- fused GEMM: 256b x 64o blocks, 64b x 64o waves -------------
// The R2/R6 wall decomposes as LDS-pipe 1536cy + MFMA 1242cy + VALU ~840cy
// per 2989cy slab-step with ~17% overlap; LDS reads are the largest term and
// scale as (o_width x K) PER WAVE regardless of b-rows. This geometry doubles
// b-rows per wave (64) at o=64, halving per-CU LDS reads (64KB/step = 768cy)
// while keeping MFMA (1242cy) and fitting 2 waves/SIMD: acc 64 AGPR + A 64 +
// frags 32 + addr ~ 205 regs (R7's 300-reg version collapsed to 1 wave/SIMD).
// Wf layout reused: a 64o block stages the 4 contiguous 1KB nt-chunks of its
// xh-half per h (linear global_load_lds). 2 slabs per barrier (4-ring pairs).
__global__ __launch_bounds__(256, 2) void k_gemm(const unsigned short* __restrict__ Wf,
                                                 const float* __restrict__ x,
                                                 const int* __restrict__ idx,
                                                 float* __restrict__ P) {
    const int tid  = threadIdx.x;
    const int wave = tid >> 6, lane = tid & 63;

    // id = zb + 4*xb + 64*yb -> XCD (id%8) = zb+4*(xb&1), constant per window.
    const int id = blockIdx.x;
    const int zb = id & 3;
    const int xb = (id >> 2) & 15;             // 64-o strip
    const int yb = id >> 6;                    // 256-b tile
    const int xbW = xb >> 1, xh = xb & 1;
    const int o0 = xb * 64, b0 = yb * 256, ibase = zb * 256;

    const char* wbase = (const char*)Wf + (size_t)(zb * 8 + xbW) * 64 * 16384
                        + (size_t)xh * 4096;
    const int   lofs  = lane * 16;

    __shared__ unsigned char sm[4][8192];      // 4-deep ring of 8KB slabs

    const int arow = b0 + wave * 64 + (lane & 15);
    const float* xg = x + (size_t)arow * IN_SZ + ibase + (lane >> 4) * 8;
    const int*   ig = idx + (size_t)arow * IN_SZ + ibase + (lane >> 4) * 8;

    floatx4 acc[16];
#pragma unroll
    for (int i = 0; i < 16; ++i) acc[i] = (floatx4){0.f, 0.f, 0.f, 0.f};

    uint4 xr[4][2], oh[4][2];                  // 64 rows x 64 i packed A state

#define RELOADA(ih)                                                           \
    {   int io_ = (ih) * 64;                                                  \
        _Pragma("unroll")                                                     \
        for (int mt_ = 0; mt_ < 4; ++mt_)                                     \
            _Pragma("unroll")                                                 \
            for (int hh_ = 0; hh_ < 2; ++hh_) {                               \
                const float* xp_ = xg + mt_ * 16 * IN_SZ + io_ + hh_ * 32;    \
                const int*   ip_ = ig + mt_ * 16 * IN_SZ + io_ + hh_ * 32;    \
                float a_[8]; int b_[8];                                       \
                *(float4*)(a_)     = *(const float4*)xp_;                     \
                *(float4*)(a_ + 4) = *((const float4*)xp_ + 1);               \
                *(int4*)(b_)       = *(const int4*)ip_;                       \
                *(int4*)(b_ + 4)   = *((const int4*)ip_ + 1);                 \
                unsigned short xv_[8];                                        \
                _Pragma("unroll")                                             \
                for (int j_ = 0; j_ < 8; ++j_) xv_[j_] = f32_to_bf16_rne(a_[j_]); \
                xr[mt_][hh_] = *(uint4*)xv_;                                  \
                uint32_t iw_[4];                                              \
                _Pragma("unroll")                                             \
                for (int w_ = 0; w_ < 4; ++w_)                                \
                    iw_[w_] = (1u << b_[2 * w_]) | ((1u << b_[2 * w_ + 1]) << 16); \
                oh[mt_][hh_] = *(uint4*)iw_;                                  \
            }                                                                 \
    }

#define MASKS(hh)                                                             \
        _Pragma("unroll")                                                     \
        for (int mt_ = 0; mt_ < 4; ++mt_) {                                   \
            aF[mt_].u.x = mask3(xr[mt_][hh].x, oh[mt_][hh].x, sh_);           \
            aF[mt_].u.y = mask3(xr[mt_][hh].y, oh[mt_][hh].y, sh_);           \
            aF[mt_].u.z = mask3(xr[mt_][hh].z, oh[mt_][hh].z, sh_);           \
            aF[mt_].u.w = mask3(xr[mt_][hh].w, oh[mt_][hh].w, sh_);           \
        }

    // stage slab s_ (8KB: h*4KB, 4 nt-chunks each) into ring slot r_.
    // wave w: src piece h = w>>1, 2KB half = w&1; dest linear in lane order.
    const int hsel = (wave >> 1), qsel = (wave & 1);
    const int sofs = hsel * 8192 + qsel * 2048 + lofs;   // source byte offset
    const int dofs = hsel * 4096 + qsel * 2048 + lofs;   // dest byte offset
#define STAGE(s_, r_)                                                         \
    {   const char* gp_ = wbase + (size_t)(s_) * 16384 + sofs;                \
        unsigned char* lp_ = (unsigned char*)sm + (r_) * 8192 + dofs;         \
        gload_lds16(gp_,        lp_);                                         \
        gload_lds16(gp_ + 1024, lp_ + 1024);                                  \
    }

// one slab from ring slot r_: h0 frags at 0..4095, h1 at 4096..8191
#define SLABC(s_, r_)                                                         \
    {   const unsigned short sh_ = (unsigned short)(15 - ((s_) & 15));        \
        union { uint4 u; short8 s8; } aF[4];                                  \
        short8 f0[4], f1[4];                                                  \
        const unsigned char* bp_ = (const unsigned char*)sm + (r_) * 8192 + lofs; \
        _Pragma("unroll")                                                     \
        for (int nt_ = 0; nt_ < 4; ++nt_)                                     \
            f0[nt_] = *(const short8*)(bp_ + nt_ * 1024);                     \
        _Pragma("unroll")                                                     \
        for (int nt_ = 0; nt_ < 4; ++nt_)                                     \
            f1[nt_] = *(const short8*)(bp_ + 4096 + nt_ * 1024);              \
        MASKS(0);                                                             \
        _Pragma("unroll")                                                     \
        for (int mt_ = 0; mt_ < 4; ++mt_)                                     \
            _Pragma("unroll")                                                 \
            for (int nt_ = 0; nt_ < 4; ++nt_)                                 \
                acc[mt_ * 4 + nt_] = __builtin_amdgcn_mfma_f32_16x16x32_bf16( \
                    aF[mt_].s8, f0[nt_], acc[mt_ * 4 + nt_], 0, 0, 0);        \
        MASKS(1);                                                             \
        _Pragma("unroll")                                                     \
        for (int mt_ = 0; mt_ < 4; ++mt_)                                     \
            _Pragma("unroll")                                                 \
            for (int nt_ = 0; nt_ < 4; ++nt_)                                 \
                acc[mt_ * 4 + nt_] = __builtin_amdgcn_mfma_f32_16x16x32_bf16( \
                    aF[mt_].s8, f1[nt_], acc[mt_ * 4 + nt_], 0, 0, 0);        \
    }

    RELOADA(0);
    STAGE(0, 0);
    STAGE(1, 1);
    __syncthreads();                           // slabs 0,1 resident

    // 2 slabs per barrier: consume ring pair {s0&3, s0+1&3}, stage the other
    // pair (no slot conflict: pairs alternate {0,1}/{2,3}).
#pragma unroll 1
    for (int gg = 0; gg < 32; ++gg) {
        if (gg && (gg & 7) == 0) RELOADA(gg >> 3);   // s = 16,32,48
        const int s0 = 2 * gg;
        if (gg < 31) {
            STAGE(s0 + 2, (s0 + 2) & 3);
            STAGE(s0 + 3, (s0 + 3) & 3);
        }
        SLABC(s0,     s0 & 3);
        SLABC(s0 + 1, (s0 + 1) & 3);
        __syncthreads();
    }

    // epilogue: plain stores to private partial buffer (C/D: col=lane&15 -> o,
    // row=(lane>>4)*4+e -> b). No atomics anywhere.
    float* Pz = P + (size_t)zb * (B_SZ * OUT_SZ);
    int cn = lane & 15, rq = lane >> 4;
#pragma unroll
    for (int mt = 0; mt < 4; ++mt)
#pragma unroll
        for (int nt = 0; nt < 4; ++nt) {
            int bb = b0 + wave * 64 + mt * 16 + rq * 4;
            int oo = o0 + nt * 16 + cn;
#pragma unroll
            for (int e = 0; e < 4; ++e)
                Pz[(size_t)(bb + e) * OUT_SZ + oo] = acc[mt * 4 + nt][e];
        }
#undef RELOADA
#undef MASKS
#undef STAGE
#undef SLABC
}

// ---------------- reduce: out = bias + sum_z P[z] ----------------
__global__ void k_reduce(const float* __restrict__ P, const float* __restrict__ bias,
                         float* __restrict__ out) {
    int t = blockIdx.x * 256 + threadIdx.x;    // float4 index, 524288 total
    const float4* b4 = (const float4*)bias;
    float4 a = b4[t & 255];
#pragma unroll
    for (int z = 0; z < NZB; ++z) {
        float4 v = ((const float4*)P)[(size_t)z * (B_SZ * OUT_SZ / 4) + t];
        a.x += v.x; a.y += v.y; a.z += v.z; a.w += v.w;
    }
    ((float4*)out)[t] = a;
}

// ---------------- fallback (ws too small): exact fp32 gather ----------------
__global__ void k_naive(const float* __restrict__ x, const int* __restrict__ idx,
                        const float* __restrict__ W, const float* __restrict__ bias,
                        float* __restrict__ out) {
    int b = blockIdx.x;
    int o = threadIdx.x * 4;
    float4 acc = *(const float4*)(bias + o);
    const float* xr = x + (size_t)b * IN_SZ;
    const int*   ir = idx + (size_t)b * IN_SZ;
    for (int i = 0; i < IN_SZ; ++i) {
        float xv = xr[i];
        int q = ir[i];
        float4 w4 = *(const float4*)(W + ((size_t)q * IN_SZ + i) * OUT_SZ + o);
        acc.x += xv * w4.x; acc.y += xv * w4.y;
        acc.z += xv * w4.z; acc.w += xv * w4.w;
    }
    *(float4*)(out + (size_t)b * OUT_SZ + o) = acc;
}

extern "C" void kernel_launch(void* const* d_in, const int* in_sizes, int n_in,
                              void* d_out, int out_size, void* d_ws, size_t ws_size,
                              hipStream_t stream) {
    const float* x    = (const float*)d_in[0];
    const int*   idx  = (const int*)d_in[1];
    const float* W    = (const float*)d_in[2];
    const float* bias = (const float*)d_in[3];
    float* out = (float*)d_out;

    const size_t wf_bytes = (size_t)2048 * 16384;                 // 32 MB frag-linear W
    const size_t p_bytes  = (size_t)NZB * B_SZ * OUT_SZ * 4;      // 32 MB partials
    if (ws_size < wf_bytes + p_bytes) {
        k_naive<<<dim3(B_SZ), dim3(256), 0, stream>>>(x, idx, W, bias, out);
        return;
    }
    unsigned short* Wf = (unsigned short*)d_ws;
    float* P = (float*)((char*)d_ws + wf_bytes);

    k_build_wf<<<dim3(2048), dim3(256), 0, stream>>>(W, Wf);
    k_gemm<<<dim3(4 * 16 * (B_SZ / 256)), dim3(256), 0, stream>>>(Wf, x, idx, P);
    k_reduce<<<dim3(2048), dim3(256), 0, stream>>>(P, bias, out);
}

// Round 9
// 185.179 us; speedup vs baseline: 1.0968x; 1.0967x over previous
//
#include <hip/hip_runtime.h>
#include <stdint.h>

#define B_SZ   2048
#define IN_SZ  1024
#define OUT_SZ 1024
#define Q_SZ   16
#define NZB    4                              // i-windows of 256

typedef __attribute__((ext_vector_type(8))) short short8;   // 8 bf16 (4 VGPRs)
typedef __attribute__((ext_vector_type(4))) float floatx4;  // MFMA accumulator
typedef __attribute__((ext_vector_type(2))) unsigned short u16x2;
typedef __attribute__((ext_vector_type(2))) short s16x2;

__device__ __forceinline__ unsigned short f32_to_bf16_rne(float f) {
    union { float f; uint32_t u; } v; v.f = f;
    uint32_t u = v.u;
    return (unsigned short)((u + 0x7FFFu + ((u >> 16) & 1u)) >> 16);
}

// packed 2x16-bit: out = (onehot has bit q) ? xv16 : 0, in 3 VALU ops.
__device__ __forceinline__ uint32_t mask3(uint32_t xv, uint32_t ohv, unsigned short sh) {
    union { uint32_t u; u16x2 v; s16x2 s; } t;
    t.u = ohv;
    u16x2 shv; shv.x = sh; shv.y = sh;
    t.v = t.v << shv;
    s16x2 f15; f15.x = 15; f15.y = 15;
    t.s = t.s >> f15;
    return xv & t.u;
}

// async global->LDS, 16B per lane, linear (wave-uniform base + lane*16)
__device__ __forceinline__ void gload_lds16(const void* g, void* l) {
    __builtin_amdgcn_global_load_lds(
        (const __attribute__((address_space(1))) unsigned int*)g,
        (__attribute__((address_space(3))) unsigned int*)l, 16, 0, 0);
}

// ---------------- prep: fragment-linear Wf (LDS-transpose, coalesced) -------
// Slab S = (zb*8+xb)*64 + ih*16 + q; chunk c = (h*8+nt)*64 + L; element j:
//   o = xb*128 + nt*16 + (L&15),  i = zb*256 + ih*64 + h*32 + (L>>4)*8 + j
__global__ void k_build_wf(const float* __restrict__ W, unsigned short* __restrict__ Wf) {
    const int S = blockIdx.x;
    const int q = S & 15, ih = (S >> 4) & 3, xb = (S >> 6) & 7, zb = S >> 9;
    const int t = threadIdx.x;
    const int i0 = zb * 256 + ih * 64;
    const int o0 = xb * 128;
    __shared__ unsigned short lds[64][130];    // pad 130: both phases ~2-way banks

#pragma unroll
    for (int it = 0; it < 8; ++it) {
        int r  = it * 8 + (t >> 5);
        int c4 = (t & 31) * 4;
        float4 v = *(const float4*)(W + ((size_t)(q * 1024 + i0 + r)) * 1024 + o0 + c4);
        unsigned short h0 = f32_to_bf16_rne(v.x), h1 = f32_to_bf16_rne(v.y);
        unsigned short h2 = f32_to_bf16_rne(v.z), h3 = f32_to_bf16_rne(v.w);
        *(uint32_t*)&lds[r][c4]     = (uint32_t)h0 | ((uint32_t)h1 << 16);
        *(uint32_t*)&lds[r][c4 + 2] = (uint32_t)h2 | ((uint32_t)h3 << 16);
    }
    __syncthreads();

    unsigned short* dst = Wf + (size_t)S * 8192;
#pragma unroll
    for (int it = 0; it < 4; ++it) {
        int c = it * 256 + t;
        int L = c & 63;
        int hnt = c >> 6;
        int h = hnt >> 3, nt = hnt & 7;
        int ol = nt * 16 + (L & 15);
        int il = h * 32 + (L >> 4) * 8;
        unsigned short v[8];
#pragma unroll
        for (int j = 0; j < 8; ++j) v[j] = lds[il + j][ol];
        *(uint4*)(dst + (size_t)c * 8) = *(uint4*)v;
    }
}

// ---------------- fused GEMM: wave-role stagger + setprio --------------------
// Block: 128b x 128o x (i-window 256, all 16 q) -> 64 slabs. Wave: 32b x 128o.
// R2..R8 ledger: measured step time ~= SUM(LDS 1536cy, MFMA 1242cy, VALU
// ~800cy) in every geometry -- the barrier per slab phase-locks all 4 waves
// (all mask together, all MFMA together), so the physically-parallel pipes
// serialize. Fix: waves 0,1 consume each slab h0->h1; waves 2,3 consume it
// h1->h0 (slot0 = h^hord, pure wave-uniform address arithmetic). At any
// instant half the waves are in mask-VALU, half in MFMA. setprio(1) around
// the MFMA clusters (T5 -- pays exactly when this role-split exists, m218b).
// Skeleton otherwise = R6: 4-deep ring, cross-slab pipelined ds_reads.
__global__ __launch_bounds__(256, 2) void k_gemm(const unsigned short* __restrict__ Wf,
                                                 const float* __restrict__ x,
                                                 const int* __restrict__ idx,
                                                 float* __restrict__ P) {
    const int tid  = threadIdx.x;
    const int wave = tid >> 6, lane = tid & 63;
    const int hord = (wave >> 1) & 1;          // 0: h0 first; 1: h1 first

    // id = zb + 4*xb + 32*yb -> XCD (id%8) = zb+4*(xb&1), constant per window.
    const int id = blockIdx.x;
    const int zb = id & 3;
    const int xb = (id >> 2) & 7;
    const int yb = id >> 5;
    const int o0 = xb * 128, b0 = yb * 128, ibase = zb * 256;

    const char* wbase = (const char*)Wf + (size_t)(zb * 8 + xb) * 64 * 16384;
    const int   lofs  = lane * 16;

    // slot->h mapping (wave-uniform, pure address arithmetic; no reg indexing)
    const int aoff0 = hord * 32,   aoff1 = 32 - aoff0;     // A global i-offset
    const int boff0 = hord * 8192, boff1 = 8192 - boff0;   // B LDS byte offset

    __shared__ unsigned char sm[4][16384];     // 4-deep slab ring (64 KB)

    const int arow = b0 + wave * 32 + (lane & 15);
    const float* xg = x + (size_t)arow * IN_SZ + ibase + (lane >> 4) * 8;
    const int*   ig = idx + (size_t)arow * IN_SZ + ibase + (lane >> 4) * 8;

    floatx4 acc[16];
#pragma unroll
    for (int i = 0; i < 16; ++i) acc[i] = (floatx4){0.f, 0.f, 0.f, 0.f};

    uint4 xr[2][2], oh[2][2];                  // [mt][slot] packed A operands
    short8 fc[8], fn[8];                       // pipelined B fragments

#define RELOADA(ih)                                                           \
    {   int io_ = (ih) * 64;                                                  \
        _Pragma("unroll")                                                     \
        for (int mt_ = 0; mt_ < 2; ++mt_)                                     \
            _Pragma("unroll")                                                 \
            for (int sl_ = 0; sl_ < 2; ++sl_) {                               \
                const int ao_ = (sl_ == 0) ? aoff0 : aoff1;                   \
                const float* xp_ = xg + mt_ * 16 * IN_SZ + io_ + ao_;         \
                const int*   ip_ = ig + mt_ * 16 * IN_SZ + io_ + ao_;         \
                float a_[8]; int b_[8];                                       \
                *(float4*)(a_)     = *(const float4*)xp_;                     \
                *(float4*)(a_ + 4) = *((const float4*)xp_ + 1);               \
                *(int4*)(b_)       = *(const int4*)ip_;                       \
                *(int4*)(b_ + 4)   = *((const int4*)ip_ + 1);                 \
                unsigned short xv_[8];                                        \
                _Pragma("unroll")                                             \
                for (int j_ = 0; j_ < 8; ++j_) xv_[j_] = f32_to_bf16_rne(a_[j_]); \
                xr[mt_][sl_] = *(uint4*)xv_;                                  \
                uint32_t iw_[4];                                              \
                _Pragma("unroll")                                             \
                for (int w_ = 0; w_ < 4; ++w_)                                \
                    iw_[w_] = (1u << b_[2 * w_]) | ((1u << b_[2 * w_ + 1]) << 16); \
                oh[mt_][sl_] = *(uint4*)iw_;                                  \
            }                                                                 \
    }

#define MASKS(sl)                                                             \
        _Pragma("unroll")                                                     \
        for (int mt_ = 0; mt_ < 2; ++mt_) {                                   \
            aF[mt_].u.x = mask3(xr[mt_][sl].x, oh[mt_][sl].x, sh_);           \
            aF[mt_].u.y = mask3(xr[mt_][sl].y, oh[mt_][sl].y, sh_);           \
            aF[mt_].u.z = mask3(xr[mt_][sl].z, oh[mt_][sl].z, sh_);           \
            aF[mt_].u.w = mask3(xr[mt_][sl].w, oh[mt_][sl].w, sh_);           \
        }

    // each wave stages 4KB of the 16KB slab: 4 x global_load_lds(16B)
    const int soff = wave * 4096 + lofs;
#define STAGE(s_, r_)                                                         \
    {   const char* gp_ = wbase + (size_t)(s_) * 16384 + soff;                \
        unsigned char* lp_ = (unsigned char*)sm + (r_) * 16384 + soff;        \
        gload_lds16(gp_,        lp_);                                         \
        gload_lds16(gp_ + 1024, lp_ + 1024);                                  \
        gload_lds16(gp_ + 2048, lp_ + 2048);                                  \
        gload_lds16(gp_ + 3072, lp_ + 3072);                                  \
    }

#define DSREAD(dst, rr, hofs)                                                 \
    {   const unsigned char* bp_ = (const unsigned char*)sm + (rr) * 16384 +  \
                                   (hofs) + lofs;                             \
        _Pragma("unroll")                                                     \
        for (int nt_ = 0; nt_ < 8; ++nt_)                                     \
            (dst)[nt_] = *(const short8*)(bp_ + nt_ * 1024);                  \
    }

#define MFMA16(fa)                                                            \
        __builtin_amdgcn_s_setprio(1);                                        \
        _Pragma("unroll")                                                     \
        for (int mt_ = 0; mt_ < 2; ++mt_)                                     \
            _Pragma("unroll")                                                 \
            for (int nt_ = 0; nt_ < 8; ++nt_)                                 \
                acc[mt_ * 8 + nt_] = __builtin_amdgcn_mfma_f32_16x16x32_bf16( \
                    aF[mt_].s8, (fa)[nt_], acc[mt_ * 8 + nt_], 0, 0, 0);      \
        __builtin_amdgcn_s_setprio(0);

// slab s: fn <- slot1-half of s; slot0 MFMAs consume fc (read last slab);
// fc <- slot0-half of s+1 issued before slot1 MFMAs; slot1 MFMAs consume fn.
#define SLAB(s_, rc_, rn_, rs_)                                               \
    {   if ((s_) < 62) STAGE((s_) + 2, rs_);                                  \
        DSREAD(fn, rc_, boff1);                                               \
        const unsigned short sh_ = (unsigned short)(15 - ((s_) & 15));        \
        union { uint4 u; short8 s8; } aF[2];                                  \
        MASKS(0);                                                             \
        MFMA16(fc);                                                           \
        if ((s_) < 63) DSREAD(fc, rn_, boff0);                                \
        MASKS(1);                                                             \
        MFMA16(fn);                                                           \
        __syncthreads();                                                      \
    }

    RELOADA(0);
    STAGE(0, 0);
    STAGE(1, 1);
    __syncthreads();                           // slabs 0,1 resident
    DSREAD(fc, 0, boff0);                      // (0, slot0-half)

#pragma unroll 1
    for (int gg = 0; gg < 16; ++gg) {
        if (gg && (gg & 3) == 0) RELOADA(gg >> 2);   // s = 16,32,48
        const int s0 = gg * 4;
        SLAB(s0 + 0, 0, 1, 2);
        SLAB(s0 + 1, 1, 2, 3);
        SLAB(s0 + 2, 2, 3, 0);
        SLAB(s0 + 3, 3, 0, 1);
    }

    // epilogue: plain stores to private partial buffer (C/D: col=lane&15 -> o,
    // row=(lane>>4)*4+e -> b). No atomics anywhere.
    float* Pz = P + (size_t)zb * (B_SZ * OUT_SZ);
    int cn = lane & 15, rq = lane >> 4;
#pragma unroll
    for (int mt = 0; mt < 2; ++mt)
#pragma unroll
        for (int nt = 0; nt < 8; ++nt) {
            int bb = b0 + wave * 32 + mt * 16 + rq * 4;
            int oo = o0 + nt * 16 + cn;
#pragma unroll
            for (int e = 0; e < 4; ++e)
                Pz[(size_t)(bb + e) * OUT_SZ + oo] = acc[mt * 8 + nt][e];
        }
#undef RELOADA
#undef MASKS
#undef STAGE
#undef DSREAD
#undef MFMA16
#undef SLAB
}

// ---------------- reduce: out = bias + sum_z P[z] ----------------
__global__ void k_reduce(const float* __restrict__ P, const float* __restrict__ bias,
                         float* __restrict__ out) {
    int t = blockIdx.x * 256 + threadIdx.x;    // float4 index, 524288 total
    const float4* b4 = (const float4*)bias;
    float4 a = b4[t & 255];
#pragma unroll
    for (int z = 0; z < NZB; ++z) {
        float4 v = ((const float4*)P)[(size_t)z * (B_SZ * OUT_SZ / 4) + t];
        a.x += v.x; a.y += v.y; a.z += v.z; a.w += v.w;
    }
    ((float4*)out)[t] = a;
}

// ---------------- fallback (ws too small): exact fp32 gather ----------------
__global__ void k_naive(const float* __restrict__ x, const int* __restrict__ idx,
                        const float* __restrict__ W, const float* __restrict__ bias,
                        float* __restrict__ out) {
    int b = blockIdx.x;
    int o = threadIdx.x * 4;
    float4 acc = *(const float4*)(bias + o);
    const float* xr = x + (size_t)b * IN_SZ;
    const int*   ir = idx + (size_t)b * IN_SZ;
    for (int i = 0; i < IN_SZ; ++i) {
        float xv = xr[i];
        int q = ir[i];
        float4 w4 = *(const float4*)(W + ((size_t)q * IN_SZ + i) * OUT_SZ + o);
        acc.x += xv * w4.x; acc.y += xv * w4.y;
        acc.z += xv * w4.z; acc.w += xv * w4.w;
    }
    *(float4*)(out + (size_t)b * OUT_SZ + o) = acc;
}

extern "C" void kernel_launch(void* const* d_in, const int* in_sizes, int n_in,
                              void* d_out, int out_size, void* d_ws, size_t ws_size,
                              hipStream_t stream) {
    const float* x    = (const float*)d_in[0];
    const int*   idx  = (const int*)d_in[1];
    const float* W    = (const float*)d_in[2];
    const float* bias = (const float*)d_in[3];
    float* out = (float*)d_out;

    const size_t wf_bytes = (size_t)2048 * 16384;                 // 32 MB frag-linear W
    const size_t p_bytes  = (size_t)NZB * B_SZ * OUT_SZ * 4;      // 32 MB partials
    if (ws_size < wf_bytes + p_bytes) {
        k_naive<<<dim3(B_SZ), dim3(256), 0, stream>>>(x, idx, W, bias, out);
        return;
    }
    unsigned short* Wf = (unsigned short*)d_ws;
    float* P = (float*)((char*)d_ws + wf_bytes);

    k_build_wf<<<dim3(2048), dim3(256), 0, stream>>>(W, Wf);
    k_gemm<<<dim3(NZB * 8 * (B_SZ / 128)), dim3(256), 0, stream>>>(Wf, x, idx, P);
    k_reduce<<<dim3(2048), dim3(256), 0, stream>>>(P, bias, out);
}

// Round 10
// 184.440 us; speedup vs baseline: 1.1012x; 1.0040x over previous
//
#include <hip/hip_runtime.h>
#include <stdint.h>

#define B_SZ   2048
#define IN_SZ  1024
#define OUT_SZ 1024
#define Q_SZ   16
#define NZB    4                              // i-windows of 256

typedef __attribute__((ext_vector_type(8))) short short8;   // 8 bf16 (4 VGPRs)
typedef __attribute__((ext_vector_type(4))) float floatx4;  // MFMA accumulator
typedef __attribute__((ext_vector_type(2))) unsigned short u16x2;
typedef __attribute__((ext_vector_type(2))) short s16x2;

__device__ __forceinline__ unsigned short f32_to_bf16_rne(float f) {
    union { float f; uint32_t u; } v; v.f = f;
    uint32_t u = v.u;
    return (unsigned short)((u + 0x7FFFu + ((u >> 16) & 1u)) >> 16);
}

// packed 2x16-bit: out = (onehot has bit q) ? xv16 : 0, in 3 VALU ops.
// (sh may be a runtime wave-uniform scalar: v_pk_lshlrev_b16 takes a reg.)
__device__ __forceinline__ uint32_t mask3(uint32_t xv, uint32_t ohv, unsigned short sh) {
    union { uint32_t u; u16x2 v; s16x2 s; } t;
    t.u = ohv;
    u16x2 shv; shv.x = sh; shv.y = sh;
    t.v = t.v << shv;
    s16x2 f15; f15.x = 15; f15.y = 15;
    t.s = t.s >> f15;
    return xv & t.u;
}

// async global->LDS, 16B per lane, linear (wave-uniform base + lane*16)
__device__ __forceinline__ void gload_lds16(const void* g, void* l) {
    __builtin_amdgcn_global_load_lds(
        (const __attribute__((address_space(1))) unsigned int*)g,
        (__attribute__((address_space(3))) unsigned int*)l, 16, 0, 0);
}

// ---------------- prep: fragment-linear Wf (LDS-transpose, coalesced) -------
// Slab S = (zb*8+xb)*64 + ih*16 + q; chunk c = (h*8+nt)*64 + L; element j:
//   o = xb*128 + nt*16 + (L&15),  i = zb*256 + ih*64 + h*32 + (L>>4)*8 + j
__global__ void k_build_wf(const float* __restrict__ W, unsigned short* __restrict__ Wf) {
    const int S = blockIdx.x;
    const int q = S & 15, ih = (S >> 4) & 3, xb = (S >> 6) & 7, zb = S >> 9;
    const int t = threadIdx.x;
    const int i0 = zb * 256 + ih * 64;
    const int o0 = xb * 128;
    __shared__ unsigned short lds[64][130];    // pad 130: both phases ~2-way banks

#pragma unroll
    for (int it = 0; it < 8; ++it) {
        int r  = it * 8 + (t >> 5);
        int c4 = (t & 31) * 4;
        float4 v = *(const float4*)(W + ((size_t)(q * 1024 + i0 + r)) * 1024 + o0 + c4);
        unsigned short h0 = f32_to_bf16_rne(v.x), h1 = f32_to_bf16_rne(v.y);
        unsigned short h2 = f32_to_bf16_rne(v.z), h3 = f32_to_bf16_rne(v.w);
        *(uint32_t*)&lds[r][c4]     = (uint32_t)h0 | ((uint32_t)h1 << 16);
        *(uint32_t*)&lds[r][c4 + 2] = (uint32_t)h2 | ((uint32_t)h3 << 16);
    }
    __syncthreads();

    unsigned short* dst = Wf + (size_t)S * 8192;
#pragma unroll
    for (int it = 0; it < 4; ++it) {
        int c = it * 256 + t;
        int L = c & 63;
        int hnt = c >> 6;
        int h = hnt >> 3, nt = hnt & 7;
        int ol = nt * 16 + (L & 15);
        int il = h * 32 + (L >> 4) * 8;
        unsigned short v[8];
#pragma unroll
        for (int j = 0; j < 8; ++j) v[j] = lds[il + j][ol];
        *(uint4*)(dst + (size_t)c * 8) = *(uint4*)v;
    }
}

// ---------------- fused GEMM: 4-way phase stagger over slab-pairs ------------
// Block: 128b x 128o; wave: 32b x 128o. R9 (2-way h-stagger) cut the step
// 2990->2756cy; residual serialization = half the waves still in-phase + 64
// re-locking barriers. Here each PAIR of slabs (same i-range, q and q+1) is
// 4 phases {s:h0, s:h1, s+1:h0, s+1:h1}; wave w starts at phase w, so the 4
// waves always occupy 4 distinct phases (VALU/MFMA/LDS maximally mixed), and
// barriers halve to one per pair. Phase->(slab,h) mapping is baked into
// per-wave ADDRESS scalars (compile-time reg indices everywhere, rule #20):
// A-regs by slot parity (parity p holds h=(w+p)&1 via aoff), B by 4
// precomputed byte-offsets per ring parity. Mask shift per slot is a
// wave-uniform runtime scalar. Ring/staging/epilogue/setprio as R9.
__global__ __launch_bounds__(256, 2) void k_gemm(const unsigned short* __restrict__ Wf,
                                                 const float* __restrict__ x,
                                                 const int* __restrict__ idx,
                                                 float* __restrict__ P) {
    const int tid  = threadIdx.x;
    const int wave = tid >> 6, lane = tid & 63;

    // id = zb + 4*xb + 32*yb -> XCD (id%8) = zb+4*(xb&1), constant per window.
    const int id = blockIdx.x;
    const int zb = id & 3;
    const int xb = (id >> 2) & 7;
    const int yb = id >> 5;
    const int o0 = xb * 128, b0 = yb * 128, ibase = zb * 256;

    const char* wbase = (const char*)Wf + (size_t)(zb * 8 + xb) * 64 * 16384;
    const int   lofs  = lane * 16;

    // 4-way phase mapping: slot k -> phase (wave+k)&3 -> (sel = slab ofs, hh)
    const int ph0 = wave & 3, ph1 = (wave + 1) & 3,
              ph2 = (wave + 2) & 3, ph3 = (wave + 3) & 3;
    const int sel0 = ph0 >> 1, sel1 = ph1 >> 1, sel2 = ph2 >> 1, sel3 = ph3 >> 1;
    const int hh0 = ph0 & 1, hh1 = ph1 & 1, hh2 = ph2 & 1, hh3 = ph3 & 1;
    // B LDS byte offsets for ring parity rbase=0 and rbase=2
    const int bo0_0 = ((0 + sel0) & 3) * 16384 + hh0 * 8192 + lofs;
    const int bo1_0 = ((0 + sel1) & 3) * 16384 + hh1 * 8192 + lofs;
    const int bo2_0 = ((0 + sel2) & 3) * 16384 + hh2 * 8192 + lofs;
    const int bo3_0 = ((0 + sel3) & 3) * 16384 + hh3 * 8192 + lofs;
    const int bo0_2 = ((2 + sel0) & 3) * 16384 + hh0 * 8192 + lofs;
    const int bo1_2 = ((2 + sel1) & 3) * 16384 + hh1 * 8192 + lofs;
    const int bo2_2 = ((2 + sel2) & 3) * 16384 + hh2 * 8192 + lofs;
    const int bo3_2 = ((2 + sel3) & 3) * 16384 + hh3 * 8192 + lofs;
    // A i-offsets by slot parity: parity p holds h=(wave+p)&1
    const int aoff0 = (wave & 1) * 32, aoff1 = 32 - aoff0;

    __shared__ unsigned char sm[4][16384];     // 4-deep slab ring (64 KB)

    const int arow = b0 + wave * 32 + (lane & 15);
    const float* xg = x + (size_t)arow * IN_SZ + ibase + (lane >> 4) * 8;
    const int*   ig = idx + (size_t)arow * IN_SZ + ibase + (lane >> 4) * 8;

    floatx4 acc[16];
#pragma unroll
    for (int i = 0; i < 16; ++i) acc[i] = (floatx4){0.f, 0.f, 0.f, 0.f};

    uint4 xr[2][2], oh[2][2];                  // [mt][parity] packed A operands
    short8 fA[8], fB[8];                       // alternating B fragments

#define RELOADA(ih)                                                           \
    {   int io_ = (ih) * 64;                                                  \
        _Pragma("unroll")                                                     \
        for (int mt_ = 0; mt_ < 2; ++mt_)                                     \
            _Pragma("unroll")                                                 \
            for (int sl_ = 0; sl_ < 2; ++sl_) {                               \
                const int ao_ = (sl_ == 0) ? aoff0 : aoff1;                   \
                const float* xp_ = xg + mt_ * 16 * IN_SZ + io_ + ao_;         \
                const int*   ip_ = ig + mt_ * 16 * IN_SZ + io_ + ao_;         \
                float a_[8]; int b_[8];                                       \
                *(float4*)(a_)     = *(const float4*)xp_;                     \
                *(float4*)(a_ + 4) = *((const float4*)xp_ + 1);               \
                *(int4*)(b_)       = *(const int4*)ip_;                       \
                *(int4*)(b_ + 4)   = *((const int4*)ip_ + 1);                 \
                unsigned short xv_[8];                                        \
                _Pragma("unroll")                                             \
                for (int j_ = 0; j_ < 8; ++j_) xv_[j_] = f32_to_bf16_rne(a_[j_]); \
                xr[mt_][sl_] = *(uint4*)xv_;                                  \
                uint32_t iw_[4];                                              \
                _Pragma("unroll")                                             \
                for (int w_ = 0; w_ < 4; ++w_)                                \
                    iw_[w_] = (1u << b_[2 * w_]) | ((1u << b_[2 * w_ + 1]) << 16); \
                oh[mt_][sl_] = *(uint4*)iw_;                                  \
            }                                                                 \
    }

#define MASKSP(par, shv)                                                      \
        _Pragma("unroll")                                                     \
        for (int mt_ = 0; mt_ < 2; ++mt_) {                                   \
            aF[mt_].u.x = mask3(xr[mt_][par].x, oh[mt_][par].x, shv);         \
            aF[mt_].u.y = mask3(xr[mt_][par].y, oh[mt_][par].y, shv);         \
            aF[mt_].u.z = mask3(xr[mt_][par].z, oh[mt_][par].z, shv);         \
            aF[mt_].u.w = mask3(xr[mt_][par].w, oh[mt_][par].w, shv);         \
        }

    // each wave stages 4KB of a 16KB slab: 4 x global_load_lds(16B)
    const int soff = wave * 4096 + lofs;
#define STAGE(s_, r_)                                                         \
    {   const char* gp_ = wbase + (size_t)(s_) * 16384 + soff;                \
        unsigned char* lp_ = (unsigned char*)sm + (r_) * 16384 + soff;        \
        gload_lds16(gp_,        lp_);                                         \
        gload_lds16(gp_ + 1024, lp_ + 1024);                                  \
        gload_lds16(gp_ + 2048, lp_ + 2048);                                  \
        gload_lds16(gp_ + 3072, lp_ + 3072);                                  \
    }

#define DSREAD(dst, boff)                                                     \
    {   const unsigned char* bp_ = (const unsigned char*)sm + (boff);         \
        _Pragma("unroll")                                                     \
        for (int nt_ = 0; nt_ < 8; ++nt_)                                     \
            (dst)[nt_] = *(const short8*)(bp_ + nt_ * 1024);                  \
    }

#define MFMA16(fa)                                                            \
        __builtin_amdgcn_s_setprio(1);                                        \
        _Pragma("unroll")                                                     \
        for (int mt_ = 0; mt_ < 2; ++mt_)                                     \
            _Pragma("unroll")                                                 \
            for (int nt_ = 0; nt_ < 8; ++nt_)                                 \
                acc[mt_ * 8 + nt_] = __builtin_amdgcn_mfma_f32_16x16x32_bf16( \
                    aF[mt_].s8, (fa)[nt_], acc[mt_ * 8 + nt_], 0, 0, 0);      \
        __builtin_amdgcn_s_setprio(0);

// one slab-pair (slabs s0_, s0_+1; 4 staggered phases; one barrier).
// Reads stay one phase ahead; stage targets are the slots NOT read this pair.
#define PAIR(s0_, bo0_, bo1_, bo2_, bo3_, dostage_, st2_, st3_)               \
    {   if (dostage_) { STAGE((s0_) + 2, st2_); STAGE((s0_) + 3, st3_); }     \
        const int q0_ = (s0_) & 15;                                           \
        const unsigned short sv0_ = (unsigned short)(15 - q0_ - sel0);        \
        const unsigned short sv1_ = (unsigned short)(15 - q0_ - sel1);        \
        const unsigned short sv2_ = (unsigned short)(15 - q0_ - sel2);        \
        const unsigned short sv3_ = (unsigned short)(15 - q0_ - sel3);        \
        union { uint4 u; short8 s8; } aF[2];                                  \
        DSREAD(fA, bo0_);                                                     \
        MASKSP(0, sv0_);                                                      \
        DSREAD(fB, bo1_);                                                     \
        MFMA16(fA);                                                           \
        MASKSP(1, sv1_);                                                      \
        DSREAD(fA, bo2_);                                                     \
        MFMA16(fB);                                                           \
        MASKSP(0, sv2_);                                                      \
        DSREAD(fB, bo3_);                                                     \
        MFMA16(fA);                                                           \
        MASKSP(1, sv3_);                                                      \
        MFMA16(fB);                                                           \
        __syncthreads();                                                      \
    }

    RELOADA(0);
    STAGE(0, 0);
    STAGE(1, 1);
    __syncthreads();                           // slabs 0,1 resident

#pragma unroll 1
    for (int gg = 0; gg < 16; ++gg) {          // 2 pairs (4 slabs) per gg
        if (gg && (gg & 3) == 0) RELOADA(gg >> 2);   // ih at s=16,32,48
        const int s0 = 4 * gg;
        PAIR(s0,     bo0_0, bo1_0, bo2_0, bo3_0, 1,       2, 3);
        PAIR(s0 + 2, bo0_2, bo1_2, bo2_2, bo3_2, gg < 15, 0, 1);
    }

    // epilogue: plain stores to private partial buffer (C/D: col=lane&15 -> o,
    // row=(lane>>4)*4+e -> b). No atomics anywhere.
    float* Pz = P + (size_t)zb * (B_SZ * OUT_SZ);
    int cn = lane & 15, rq = lane >> 4;
#pragma unroll
    for (int mt = 0; mt < 2; ++mt)
#pragma unroll
        for (int nt = 0; nt < 8; ++nt) {
            int bb = b0 + wave * 32 + mt * 16 + rq * 4;
            int oo = o0 + nt * 16 + cn;
#pragma unroll
            for (int e = 0; e < 4; ++e)
                Pz[(size_t)(bb + e) * OUT_SZ + oo] = acc[mt * 8 + nt][e];
        }
#undef RELOADA
#undef MASKSP
#undef STAGE
#undef DSREAD
#undef MFMA16
#undef PAIR
}

// ---------------- reduce: out = bias + sum_z P[z] ----------------
__global__ void k_reduce(const float* __restrict__ P, const float* __restrict__ bias,
                         float* __restrict__ out) {
    int t = blockIdx.x * 256 + threadIdx.x;    // float4 index, 524288 total
    const float4* b4 = (const float4*)bias;
    float4 a = b4[t & 255];
#pragma unroll
    for (int z = 0; z < NZB; ++z) {
        float4 v = ((const float4*)P)[(size_t)z * (B_SZ * OUT_SZ / 4) + t];
        a.x += v.x; a.y += v.y; a.z += v.z; a.w += v.w;
    }
    ((float4*)out)[t] = a;
}

// ---------------- fallback (ws too small): exact fp32 gather ----------------
__global__ void k_naive(const float* __restrict__ x, const int* __restrict__ idx,
                        const float* __restrict__ W, const float* __restrict__ bias,
                        float* __restrict__ out) {
    int b = blockIdx.x;
    int o = threadIdx.x * 4;
    float4 acc = *(const float4*)(bias + o);
    const float* xr = x + (size_t)b * IN_SZ;
    const int*   ir = idx + (size_t)b * IN_SZ;
    for (int i = 0; i < IN_SZ; ++i) {
        float xv = xr[i];
        int q = ir[i];
        float4 w4 = *(const float4*)(W + ((size_t)q * IN_SZ + i) * OUT_SZ + o);
        acc.x += xv * w4.x; acc.y += xv * w4.y;
        acc.z += xv * w4.z; acc.w += xv * w4.w;
    }
    *(float4*)(out + (size_t)b * OUT_SZ + o) = acc;
}

extern "C" void kernel_launch(void* const* d_in, const int* in_sizes, int n_in,
                              void* d_out, int out_size, void* d_ws, size_t ws_size,
                              hipStream_t stream) {
    const float* x    = (const float*)d_in[0];
    const int*   idx  = (const int*)d_in[1];
    const float* W    = (const float*)d_in[2];
    const float* bias = (const float*)d_in[3];
    float* out = (float*)d_out;

    const size_t wf_bytes = (size_t)2048 * 16384;                 // 32 MB frag-linear W
    const size_t p_bytes  = (size_t)NZB * B_SZ * OUT_SZ * 4;      // 32 MB partials
    if (ws_size < wf_bytes + p_bytes) {
        k_naive<<<dim3(B_SZ), dim3(256), 0, stream>>>(x, idx, W, bias, out);
        return;
    }
    unsigned short* Wf = (unsigned short*)d_ws;
    float* P = (float*)((char*)d_ws + wf_bytes);

    k_build_wf<<<dim3(2048), dim3(256), 0, stream>>>(W, Wf);
    k_gemm<<<dim3(NZB * 8 * (B_SZ / 128)), dim3(256), 0, stream>>>(Wf, x, idx, P);
    k_reduce<<<dim3(2048), dim3(256), 0, stream>>>(P, bias, out);
}